// Round 3
// baseline (2025.522 us; speedup 1.0000x reference)
//
#include <hip/hip_runtime.h>

// GraphNet forward, fp32 compute / bf16 edge-hidden storage.
// Round 3: kill fill_kernel's 305us scattered-4B-write sort. Bucket
// counting-sort (LDS-staged coalesced writes) + per-bucket LDS-accumulate
// gather. Scattered small WRITES cost a full 64B sector each (~700GB/s
// ceiling, measured r1/r2); scattered READS of LLC-resident e_h are cheap.

typedef unsigned int uint;
typedef unsigned short ushort;

#define BW 128          // nodes per bucket
#define BSHIFT 7
#define NBMAX 784       // max buckets (N=100000 -> 782)
#define DC 16384        // edges per distribute block
#define EMASK 0x1FFFFFu // 21 bits of edge id (E=1.6M < 2^21)

#define LDF4(p) (*reinterpret_cast<const float4*>(p))

__device__ __forceinline__ void load16(const float* __restrict__ p, float* v) {
  float4 a = LDF4(p), b = LDF4(p + 4), c = LDF4(p + 8), d = LDF4(p + 12);
  v[0]=a.x; v[1]=a.y; v[2]=a.z; v[3]=a.w;
  v[4]=b.x; v[5]=b.y; v[6]=b.z; v[7]=b.w;
  v[8]=c.x; v[9]=c.y; v[10]=c.z; v[11]=c.w;
  v[12]=d.x; v[13]=d.y; v[14]=d.z; v[15]=d.w;
}

__device__ __forceinline__ ushort f2bf(float f) {
  uint u = __float_as_uint(f);
  u += 0x7FFFu + ((u >> 16) & 1u);
  return (ushort)(u >> 16);
}
__device__ __forceinline__ float bf2f(ushort h) {
  return __uint_as_float((uint)h << 16);
}

// ---- fold uniform-u contributions into per-layer init vectors
__global__ void precompute_kernel(const float* __restrict__ u,
                                  const float* __restrict__ W_eb,
                                  const float* __restrict__ b_eb,
                                  const float* __restrict__ W_nb,
                                  const float* __restrict__ b_nb,
                                  float* __restrict__ eb_init,
                                  float* __restrict__ nb_init) {
  int j = threadIdx.x;  // 64 threads
  float ae = b_eb[j], an = b_nb[j];
  for (int k = 0; k < 64; ++k) {
    float uk = u[k];
    ae = fmaf(uk, W_eb[(48 + k) * 64 + j], ae);
    an = fmaf(uk, W_nb[(80 + k) * 64 + j], an);
  }
  eb_init[j] = ae;
  nb_init[j] = an;
}

// ---- edge MLP: e_h = relu([ea, x_r, x_s]@W[0:48] + eb_init) -> bf16
__global__ __launch_bounds__(256, 4) void edge_kernel(
    const float* __restrict__ edge_attr, const float* __restrict__ x,
    const int* __restrict__ senders, const int* __restrict__ receivers,
    const float* __restrict__ W_eb, const float* __restrict__ eb_init,
    ushort* __restrict__ e_h, int E) {
  int e = blockIdx.x * 256 + threadIdx.x;
  if (e >= E) return;
  int r = receivers[e];
  int s = senders[e];
  float v[48];
  load16(edge_attr + (size_t)e * 16, v);
  load16(x + (size_t)r * 16, v + 16);
  load16(x + (size_t)s * 16, v + 32);
  uint4* dst = reinterpret_cast<uint4*>(e_h + (size_t)e * 64);
  #pragma unroll
  for (int c = 0; c < 4; ++c) {
    float acc[16];
    #pragma unroll
    for (int j = 0; j < 16; ++j) acc[j] = eb_init[c * 16 + j];
    #pragma unroll
    for (int i = 0; i < 48; ++i) {
      const float* Wrow = W_eb + i * 64 + c * 16;
      #pragma unroll
      for (int j = 0; j < 16; ++j) acc[j] = fmaf(v[i], Wrow[j], acc[j]);
    }
    union { ushort h[16]; uint4 q[2]; } pk;
    #pragma unroll
    for (int j = 0; j < 16; ++j) pk.h[j] = f2bf(fmaxf(acc[j], 0.f));
    dst[c * 2] = pk.q[0];
    dst[c * 2 + 1] = pk.q[1];
  }
}

// ---- bucket histogram for both directions (LDS hist -> global merge)
__global__ __launch_bounds__(256) void bcount_kernel(
    const int* __restrict__ receivers, const int* __restrict__ senders,
    uint* __restrict__ bcnt_r, uint* __restrict__ bcnt_s, int E, int NB) {
  __shared__ uint hr[NBMAX], hs[NBMAX];
  int t = threadIdx.x;
  for (int i = t; i < NB; i += 256) { hr[i] = 0; hs[i] = 0; }
  __syncthreads();
  int stride = gridDim.x * 256;
  for (int e = blockIdx.x * 256 + t; e < E; e += stride) {
    atomicAdd(&hr[receivers[e] >> BSHIFT], 1u);
    atomicAdd(&hs[senders[e] >> BSHIFT], 1u);
  }
  __syncthreads();
  for (int i = t; i < NB; i += 256) {
    if (hr[i]) atomicAdd(&bcnt_r[i], hr[i]);
    if (hs[i]) atomicAdd(&bcnt_s[i], hs[i]);
  }
}

// ---- exclusive scan of both bucket-count arrays (single block)
__global__ __launch_bounds__(256) void bscan_kernel(
    const uint* __restrict__ bcnt_r, const uint* __restrict__ bcnt_s,
    uint* __restrict__ start_r, uint* __restrict__ start_s,
    uint* __restrict__ cur_r, uint* __restrict__ cur_s, int E, int NB) {
  __shared__ uint ts[256];
  int t = threadIdx.x;
  #pragma unroll
  for (int pass = 0; pass < 2; ++pass) {
    const uint* cnt = pass ? bcnt_s : bcnt_r;
    uint* start = pass ? start_s : start_r;
    uint* cur = pass ? cur_s : cur_r;
    uint loc[4]; uint tsum = 0;
    #pragma unroll
    for (int q = 0; q < 4; ++q) {
      int i = t * 4 + q;
      loc[q] = (i < NB) ? cnt[i] : 0;
      tsum += loc[q];
    }
    ts[t] = tsum;
    __syncthreads();
    for (int off = 1; off < 256; off <<= 1) {
      uint a = (t >= off) ? ts[t - off] : 0;
      __syncthreads();
      ts[t] += a;
      __syncthreads();
    }
    uint run = ts[t] - tsum;
    #pragma unroll
    for (int q = 0; q < 4; ++q) {
      int i = t * 4 + q;
      if (i < NB) { start[i] = run; cur[i] = run; run += loc[q]; }
    }
    if (t == 0) start[NB] = (uint)E;
    __syncthreads();
  }
}

// ---- bucket-sort edge ids with LDS staging -> coalesced global writes.
// tmp[slot] = (bucket<<21) | edge_id, grouped by bucket.
__global__ __launch_bounds__(256) void distribute_kernel(
    const int* __restrict__ key, uint* __restrict__ g_cursor,
    uint* __restrict__ tmp, int E, int NB) {
  __shared__ uint hist[NBMAX], lstart[NBMAX], cur[NBMAX], gbase[NBMAX];
  __shared__ uint ids[DC];
  __shared__ uint ts[256];
  int t = threadIdx.x;
  int base = blockIdx.x * DC;
  int cact = min(DC, E - base);
  for (int i = t; i < NB; i += 256) hist[i] = 0;
  __syncthreads();
  // pass 1: count
  for (int k = 0; k < DC / 256; ++k) {
    int j = k * 256 + t;
    if (j < cact) atomicAdd(&hist[key[base + j] >> BSHIFT], 1u);
  }
  __syncthreads();
  // exclusive scan hist -> lstart, init cur
  {
    uint loc[4]; uint tsum = 0;
    #pragma unroll
    for (int q = 0; q < 4; ++q) {
      int i = t * 4 + q;
      loc[q] = (i < NB) ? hist[i] : 0;
      tsum += loc[q];
    }
    ts[t] = tsum;
    __syncthreads();
    for (int off = 1; off < 256; off <<= 1) {
      uint a = (t >= off) ? ts[t - off] : 0;
      __syncthreads();
      ts[t] += a;
      __syncthreads();
    }
    uint run = ts[t] - tsum;
    #pragma unroll
    for (int q = 0; q < 4; ++q) {
      int i = t * 4 + q;
      if (i < NB) { lstart[i] = run; cur[i] = run; run += loc[q]; }
    }
  }
  __syncthreads();
  // reserve global runs
  for (int i = t; i < NB; i += 256)
    if (hist[i]) gbase[i] = atomicAdd(&g_cursor[i], hist[i]);
  // pass 2: stage into LDS grouped by bucket
  for (int k = 0; k < DC / 256; ++k) {
    int j = k * 256 + t;
    if (j < cact) {
      int e = base + j;
      uint b = (uint)(key[e] >> BSHIFT);
      uint slot = atomicAdd(&cur[b], 1u);
      ids[slot] = (b << 21) | (uint)e;
    }
  }
  __syncthreads();
  // coalesced write-out
  for (int j = t; j < cact; j += 256) {
    uint v = ids[j];
    uint b = v >> 21;
    tmp[gbase[b] + ((uint)j - lstart[b])] = v;
  }
}

// ---- per-bucket gather: LDS fp32 accumulate of e_h rows + per-node counts
__global__ __launch_bounds__(256, 4) void gather_kernel(
    const ushort* __restrict__ e_h, const int* __restrict__ key,
    const uint* __restrict__ start, const uint* __restrict__ tmp,
    float* __restrict__ sum, uint* __restrict__ cnt, int N) {
  __shared__ float acc[BW * 64];  // 32 KB
  __shared__ uint cntL[BW];
  int b = blockIdx.x;
  int t = threadIdx.x;
  for (int i = t; i < BW * 64; i += 256) acc[i] = 0.f;
  for (int i = t; i < BW; i += 256) cntL[i] = 0;
  __syncthreads();
  int beg = (int)start[b], end = (int)start[b + 1];
  int wid = t >> 6, lane = t & 63;
  int i = beg + wid;
  for (; i + 4 < end; i += 8) {
    uint v0 = tmp[i], v1 = tmp[i + 4];
    int e0 = (int)(v0 & EMASK), e1 = (int)(v1 & EMASK);
    int r0 = key[e0] & (BW - 1), r1 = key[e1] & (BW - 1);
    float h0 = bf2f(e_h[(size_t)e0 * 64 + lane]);
    float h1 = bf2f(e_h[(size_t)e1 * 64 + lane]);
    atomicAdd(&acc[r0 * 64 + lane], h0);
    atomicAdd(&acc[r1 * 64 + lane], h1);
    if (lane == 0) { atomicAdd(&cntL[r0], 1u); atomicAdd(&cntL[r1], 1u); }
  }
  for (; i < end; i += 4) {
    uint v = tmp[i];
    int e = (int)(v & EMASK);
    int rl = key[e] & (BW - 1);
    float h = bf2f(e_h[(size_t)e * 64 + lane]);
    atomicAdd(&acc[rl * 64 + lane], h);
    if (lane == 0) atomicAdd(&cntL[rl], 1u);
  }
  __syncthreads();
  int nbase = b * BW;
  for (int i2 = t; i2 < BW * 64; i2 += 256) {
    int node = nbase + (i2 >> 6);
    if (node < N) sum[(size_t)node * 64 + (i2 & 63)] = acc[i2];
  }
  for (int i2 = t; i2 < BW; i2 += 256)
    if (nbase + i2 < N) cnt[nbase + i2] = cntL[i2];
}

// ---- node block
__global__ __launch_bounds__(256, 4) void node_kernel(
    const float* __restrict__ x, const float* __restrict__ sum_recv,
    const float* __restrict__ W_nb, const float* __restrict__ nb_init,
    float* __restrict__ n_h, int N) {
  int n = blockIdx.x * 256 + threadIdx.x;
  if (n >= N) return;
  float v[80];
  const float* ar = sum_recv + (size_t)n * 64;
  load16(ar, v); load16(ar + 16, v + 16); load16(ar + 32, v + 32);
  load16(ar + 48, v + 48);
  load16(x + (size_t)n * 16, v + 64);
  float* out = n_h + (size_t)n * 64;
  #pragma unroll
  for (int c = 0; c < 4; ++c) {
    float acc[16];
    #pragma unroll
    for (int j = 0; j < 16; ++j) acc[j] = nb_init[c * 16 + j];
    #pragma unroll
    for (int i = 0; i < 80; ++i) {
      const float* Wrow = W_nb + i * 64 + c * 16;
      #pragma unroll
      for (int j = 0; j < 16; ++j) acc[j] = fmaf(v[i], Wrow[j], acc[j]);
    }
    #pragma unroll
    for (int j = 0; j < 16; j += 4) {
      float4 tq = {fmaxf(acc[j], 0.f), fmaxf(acc[j + 1], 0.f),
                   fmaxf(acc[j + 2], 0.f), fmaxf(acc[j + 3], 0.f)};
      *reinterpret_cast<float4*>(out + c * 16 + j) = tq;
    }
  }
}

// ---- column sums of sum_recv (= sum of all e_h) and n_h
__global__ __launch_bounds__(256) void reduce_kernel(
    const float* __restrict__ sum_recv, const float* __restrict__ n_h,
    float* __restrict__ e_sum, float* __restrict__ n_sum, int N) {
  __shared__ float ls[128];
  if (threadIdx.x < 128) ls[threadIdx.x] = 0.f;
  __syncthreads();
  int g = threadIdx.x & 15;
  int tid = blockIdx.x * blockDim.x + threadIdx.x;
  int row0 = tid >> 4;
  int rstride = (gridDim.x * blockDim.x) >> 4;
  float pe[4] = {0, 0, 0, 0}, pn[4] = {0, 0, 0, 0};
  for (int r = row0; r < N; r += rstride) {
    float4 a = LDF4(sum_recv + (size_t)r * 64 + g * 4);
    float4 b = LDF4(n_h + (size_t)r * 64 + g * 4);
    pe[0] += a.x; pe[1] += a.y; pe[2] += a.z; pe[3] += a.w;
    pn[0] += b.x; pn[1] += b.y; pn[2] += b.z; pn[3] += b.w;
  }
  #pragma unroll
  for (int i = 0; i < 4; ++i) {
    atomicAdd(&ls[g * 4 + i], pe[i]);
    atomicAdd(&ls[64 + g * 4 + i], pn[i]);
  }
  __syncthreads();
  if (threadIdx.x < 64) {
    atomicAdd(&e_sum[threadIdx.x], ls[threadIdx.x]);
    atomicAdd(&n_sum[threadIdx.x], ls[64 + threadIdx.x]);
  }
}

// ---- global block + fold u2 into d1_init
__global__ void global_kernel(const float* __restrict__ u,
                              const float* __restrict__ e_sum,
                              const float* __restrict__ n_sum,
                              const float* __restrict__ W_gb,
                              const float* __restrict__ b_gb,
                              const float* __restrict__ W_d1,
                              const float* __restrict__ b_d1,
                              float* __restrict__ d1_init, float Ef, float Nf) {
  __shared__ float gin[192];
  __shared__ float u2s[64];
  int j = threadIdx.x;  // 64 threads
  gin[j] = e_sum[j] / Ef;
  gin[64 + j] = n_sum[j] / Nf;
  gin[128 + j] = u[j];
  __syncthreads();
  float a = b_gb[j];
  for (int k = 0; k < 192; ++k) a = fmaf(gin[k], W_gb[k * 64 + j], a);
  u2s[j] = fmaxf(a, 0.f);
  __syncthreads();
  float d = b_d1[j];
  for (int k = 0; k < 64; ++k) d = fmaf(u2s[k], W_d1[(192 + k) * 64 + j], d);
  d1_init[j] = d;
}

// ---- decoder
__global__ __launch_bounds__(256, 2) void decoder_kernel(
    const float* __restrict__ sum_recv, const float* __restrict__ sum_sent,
    const uint* __restrict__ cnt_r, const uint* __restrict__ cnt_s,
    const float* __restrict__ n_h, const float* __restrict__ W_d1,
    const float* __restrict__ d1_init, const float* __restrict__ W_d2,
    const float* __restrict__ b_d2, float* __restrict__ out, int N) {
  int n = blockIdx.x * 256 + threadIdx.x;
  if (n >= N) return;
  float acc[64];
  #pragma unroll
  for (int j = 0; j < 64; ++j) acc[j] = d1_init[j];
  float v[16];
  float invr = 1.0f / fmaxf((float)cnt_r[n], 1.0f);
  const float* pr = sum_recv + (size_t)n * 64;
  #pragma unroll
  for (int c = 0; c < 4; ++c) {
    load16(pr + c * 16, v);
    #pragma unroll
    for (int i = 0; i < 16; ++i) v[i] *= invr;
    #pragma unroll
    for (int i = 0; i < 16; ++i) {
      const float* Wrow = W_d1 + (c * 16 + i) * 64;
      #pragma unroll
      for (int j = 0; j < 64; ++j) acc[j] = fmaf(v[i], Wrow[j], acc[j]);
    }
  }
  float invs = 1.0f / fmaxf((float)cnt_s[n], 1.0f);
  const float* ps = sum_sent + (size_t)n * 64;
  #pragma unroll
  for (int c = 0; c < 4; ++c) {
    load16(ps + c * 16, v);
    #pragma unroll
    for (int i = 0; i < 16; ++i) v[i] *= invs;
    #pragma unroll
    for (int i = 0; i < 16; ++i) {
      const float* Wrow = W_d1 + (64 + c * 16 + i) * 64;
      #pragma unroll
      for (int j = 0; j < 64; ++j) acc[j] = fmaf(v[i], Wrow[j], acc[j]);
    }
  }
  const float* pn = n_h + (size_t)n * 64;
  #pragma unroll
  for (int c = 0; c < 4; ++c) {
    load16(pn + c * 16, v);
    #pragma unroll
    for (int i = 0; i < 16; ++i) {
      const float* Wrow = W_d1 + (128 + c * 16 + i) * 64;
      #pragma unroll
      for (int j = 0; j < 64; ++j) acc[j] = fmaf(v[i], Wrow[j], acc[j]);
    }
  }
  #pragma unroll
  for (int j = 0; j < 64; ++j) acc[j] = fmaxf(acc[j], 0.f);
  float* po = out + (size_t)n * 16;
  #pragma unroll
  for (int o = 0; o < 16; o += 4) {
    float4 tq;
    float* tp = &tq.x;
    #pragma unroll
    for (int q = 0; q < 4; ++q) {
      float a = b_d2[o + q];
      #pragma unroll
      for (int j = 0; j < 64; ++j) a = fmaf(acc[j], W_d2[j * 16 + o + q], a);
      tp[q] = a;
    }
    *reinterpret_cast<float4*>(po + o) = tq;
  }
}

extern "C" void kernel_launch(void* const* d_in, const int* in_sizes, int n_in,
                              void* d_out, int out_size, void* d_ws,
                              size_t ws_size, hipStream_t stream) {
  const float* x         = (const float*)d_in[0];
  const float* edge_attr = (const float*)d_in[1];
  const float* u         = (const float*)d_in[2];
  const int*   senders   = (const int*)d_in[3];
  const int*   receivers = (const int*)d_in[4];
  const float* W_eb = (const float*)d_in[7];
  const float* b_eb = (const float*)d_in[8];
  const float* W_nb = (const float*)d_in[9];
  const float* b_nb = (const float*)d_in[10];
  const float* W_gb = (const float*)d_in[11];
  const float* b_gb = (const float*)d_in[12];
  const float* W_d1 = (const float*)d_in[13];
  const float* b_d1 = (const float*)d_in[14];
  const float* W_d2 = (const float*)d_in[15];
  const float* b_d2 = (const float*)d_in[16];

  int N = in_sizes[0] / 16;
  int E = in_sizes[1] / 16;
  int NB = (N + BW - 1) >> BSHIFT;  // 782 for N=100000

  char* w = (char*)d_ws;
  ushort* e_h = (ushort*)w;          w += (size_t)E * 64 * 2;
  float* sum_recv = (float*)w;       w += (size_t)N * 64 * 4;
  float* sum_sent = (float*)w;       w += (size_t)N * 64 * 4;
  float* n_h = (float*)w;            w += (size_t)N * 64 * 4;
  uint* tmp_r = (uint*)w;            w += (size_t)E * 4;
  uint* tmp_s = (uint*)w;            w += (size_t)E * 4;
  uint* start_r = (uint*)w;          w += (size_t)(NB + 1) * 4;
  uint* start_s = (uint*)w;          w += (size_t)(NB + 1) * 4;
  uint* cur_r = (uint*)w;            w += (size_t)NB * 4;
  uint* cur_s = (uint*)w;            w += (size_t)NB * 4;
  uint* cnt_r = (uint*)w;            w += (size_t)N * 4;
  uint* cnt_s = (uint*)w;            w += (size_t)N * 4;
  // zeroed region
  uint* bcnt_r = (uint*)w;           w += (size_t)NBMAX * 4;
  uint* bcnt_s = (uint*)w;           w += (size_t)NBMAX * 4;
  float* e_sum = (float*)w;          w += 64 * 4;
  float* n_sum = (float*)w;          w += 64 * 4;
  // small non-zeroed
  float* eb_init = (float*)w;        w += 64 * 4;
  float* nb_init = (float*)w;        w += 64 * 4;
  float* d1_init = (float*)w;        w += 64 * 4;

  size_t zero_bytes = (size_t)(2 * NBMAX + 128) * 4;
  hipMemsetAsync(bcnt_r, 0, zero_bytes, stream);

  hipLaunchKernelGGL(precompute_kernel, dim3(1), dim3(64), 0, stream, u, W_eb,
                     b_eb, W_nb, b_nb, eb_init, nb_init);
  hipLaunchKernelGGL(edge_kernel, dim3((E + 255) / 256), dim3(256), 0, stream,
                     edge_attr, x, senders, receivers, W_eb, eb_init, e_h, E);
  hipLaunchKernelGGL(bcount_kernel, dim3(64), dim3(256), 0, stream, receivers,
                     senders, bcnt_r, bcnt_s, E, NB);
  hipLaunchKernelGGL(bscan_kernel, dim3(1), dim3(256), 0, stream, bcnt_r,
                     bcnt_s, start_r, start_s, cur_r, cur_s, E, NB);
  hipLaunchKernelGGL(distribute_kernel, dim3((E + DC - 1) / DC), dim3(256), 0,
                     stream, receivers, cur_r, tmp_r, E, NB);
  hipLaunchKernelGGL(distribute_kernel, dim3((E + DC - 1) / DC), dim3(256), 0,
                     stream, senders, cur_s, tmp_s, E, NB);
  hipLaunchKernelGGL(gather_kernel, dim3(NB), dim3(256), 0, stream, e_h,
                     receivers, start_r, tmp_r, sum_recv, cnt_r, N);
  hipLaunchKernelGGL(gather_kernel, dim3(NB), dim3(256), 0, stream, e_h,
                     senders, start_s, tmp_s, sum_sent, cnt_s, N);
  hipLaunchKernelGGL(node_kernel, dim3((N + 255) / 256), dim3(256), 0, stream,
                     x, sum_recv, W_nb, nb_init, n_h, N);
  hipLaunchKernelGGL(reduce_kernel, dim3(256), dim3(256), 0, stream, sum_recv,
                     n_h, e_sum, n_sum, N);
  hipLaunchKernelGGL(global_kernel, dim3(1), dim3(64), 0, stream, u, e_sum,
                     n_sum, W_gb, b_gb, W_d1, b_d1, d1_init, (float)E,
                     (float)N);
  hipLaunchKernelGGL(decoder_kernel, dim3((N + 255) / 256), dim3(256), 0,
                     stream, sum_recv, sum_sent, cnt_r, cnt_s, n_h, W_d1,
                     d1_init, W_d2, b_d2, (float*)d_out, N);
}

// Round 4
// 1929.366 us; speedup vs baseline: 1.0498x; 1.0498x over previous
//
#include <hip/hip_runtime.h>

// GraphNet forward, fp32 compute / bf16 edge-hidden storage.
// Round 4: gather was LATENCY-bound (716us, occ 22%, VALU 4.6%, 263GB/s).
// Fix concurrency: 512-thr blocks, half-wave edge units, unroll 4 (8KB rows
// in flight per block), uint e_h loads. Fuse the two distribute launches
// (grid 98 was under-filling 256 CUs) with DC=8192.

typedef unsigned int uint;
typedef unsigned short ushort;

#define BW 128          // nodes per bucket
#define BSHIFT 7
#define NBMAX 784       // max buckets (N=100000 -> 782)
#define DC 8192         // edges per distribute block
#define EMASK 0x1FFFFFu // 21 bits of edge id (E=1.6M < 2^21)
#define ASTRIDE 65      // LDS acc row stride (bank-parity mix)

#define LDF4(p) (*reinterpret_cast<const float4*>(p))

__device__ __forceinline__ void load16(const float* __restrict__ p, float* v) {
  float4 a = LDF4(p), b = LDF4(p + 4), c = LDF4(p + 8), d = LDF4(p + 12);
  v[0]=a.x; v[1]=a.y; v[2]=a.z; v[3]=a.w;
  v[4]=b.x; v[5]=b.y; v[6]=b.z; v[7]=b.w;
  v[8]=c.x; v[9]=c.y; v[10]=c.z; v[11]=c.w;
  v[12]=d.x; v[13]=d.y; v[14]=d.z; v[15]=d.w;
}

__device__ __forceinline__ ushort f2bf(float f) {
  uint u = __float_as_uint(f);
  u += 0x7FFFu + ((u >> 16) & 1u);
  return (ushort)(u >> 16);
}

// ---- fold uniform-u contributions into per-layer init vectors
__global__ void precompute_kernel(const float* __restrict__ u,
                                  const float* __restrict__ W_eb,
                                  const float* __restrict__ b_eb,
                                  const float* __restrict__ W_nb,
                                  const float* __restrict__ b_nb,
                                  float* __restrict__ eb_init,
                                  float* __restrict__ nb_init) {
  int j = threadIdx.x;  // 64 threads
  float ae = b_eb[j], an = b_nb[j];
  for (int k = 0; k < 64; ++k) {
    float uk = u[k];
    ae = fmaf(uk, W_eb[(48 + k) * 64 + j], ae);
    an = fmaf(uk, W_nb[(80 + k) * 64 + j], an);
  }
  eb_init[j] = ae;
  nb_init[j] = an;
}

// ---- edge MLP: e_h = relu([ea, x_r, x_s]@W[0:48] + eb_init) -> bf16
__global__ __launch_bounds__(256, 4) void edge_kernel(
    const float* __restrict__ edge_attr, const float* __restrict__ x,
    const int* __restrict__ senders, const int* __restrict__ receivers,
    const float* __restrict__ W_eb, const float* __restrict__ eb_init,
    ushort* __restrict__ e_h, int E) {
  int e = blockIdx.x * 256 + threadIdx.x;
  if (e >= E) return;
  int r = receivers[e];
  int s = senders[e];
  float v[48];
  load16(edge_attr + (size_t)e * 16, v);
  load16(x + (size_t)r * 16, v + 16);
  load16(x + (size_t)s * 16, v + 32);
  uint4* dst = reinterpret_cast<uint4*>(e_h + (size_t)e * 64);
  #pragma unroll
  for (int c = 0; c < 4; ++c) {
    float acc[16];
    #pragma unroll
    for (int j = 0; j < 16; ++j) acc[j] = eb_init[c * 16 + j];
    #pragma unroll
    for (int i = 0; i < 48; ++i) {
      const float* Wrow = W_eb + i * 64 + c * 16;
      #pragma unroll
      for (int j = 0; j < 16; ++j) acc[j] = fmaf(v[i], Wrow[j], acc[j]);
    }
    union { ushort h[16]; uint4 q[2]; } pk;
    #pragma unroll
    for (int j = 0; j < 16; ++j) pk.h[j] = f2bf(fmaxf(acc[j], 0.f));
    dst[c * 2] = pk.q[0];
    dst[c * 2 + 1] = pk.q[1];
  }
}

// ---- bucket histogram for both directions (LDS hist -> global merge)
__global__ __launch_bounds__(256) void bcount_kernel(
    const int* __restrict__ receivers, const int* __restrict__ senders,
    uint* __restrict__ bcnt_r, uint* __restrict__ bcnt_s, int E, int NB) {
  __shared__ uint hr[NBMAX], hs[NBMAX];
  int t = threadIdx.x;
  for (int i = t; i < NB; i += 256) { hr[i] = 0; hs[i] = 0; }
  __syncthreads();
  int stride = gridDim.x * 256;
  for (int e = blockIdx.x * 256 + t; e < E; e += stride) {
    atomicAdd(&hr[receivers[e] >> BSHIFT], 1u);
    atomicAdd(&hs[senders[e] >> BSHIFT], 1u);
  }
  __syncthreads();
  for (int i = t; i < NB; i += 256) {
    if (hr[i]) atomicAdd(&bcnt_r[i], hr[i]);
    if (hs[i]) atomicAdd(&bcnt_s[i], hs[i]);
  }
}

// ---- exclusive scan of both bucket-count arrays (single block)
__global__ __launch_bounds__(256) void bscan_kernel(
    const uint* __restrict__ bcnt_r, const uint* __restrict__ bcnt_s,
    uint* __restrict__ start_r, uint* __restrict__ start_s,
    uint* __restrict__ cur_r, uint* __restrict__ cur_s, int E, int NB) {
  __shared__ uint ts[256];
  int t = threadIdx.x;
  #pragma unroll
  for (int pass = 0; pass < 2; ++pass) {
    const uint* cnt = pass ? bcnt_s : bcnt_r;
    uint* start = pass ? start_s : start_r;
    uint* cur = pass ? cur_s : cur_r;
    uint loc[4]; uint tsum = 0;
    #pragma unroll
    for (int q = 0; q < 4; ++q) {
      int i = t * 4 + q;
      loc[q] = (i < NB) ? cnt[i] : 0;
      tsum += loc[q];
    }
    ts[t] = tsum;
    __syncthreads();
    for (int off = 1; off < 256; off <<= 1) {
      uint a = (t >= off) ? ts[t - off] : 0;
      __syncthreads();
      ts[t] += a;
      __syncthreads();
    }
    uint run = ts[t] - tsum;
    #pragma unroll
    for (int q = 0; q < 4; ++q) {
      int i = t * 4 + q;
      if (i < NB) { start[i] = run; cur[i] = run; run += loc[q]; }
    }
    if (t == 0) start[NB] = (uint)E;
    __syncthreads();
  }
}

// ---- bucket-sort edge ids, both directions in one launch.
// even blocks: receivers; odd blocks: senders. LDS-staged coalesced writes.
__global__ __launch_bounds__(256) void distribute_kernel(
    const int* __restrict__ receivers, const int* __restrict__ senders,
    uint* __restrict__ gcur_r, uint* __restrict__ gcur_s,
    uint* __restrict__ tmp_r, uint* __restrict__ tmp_s, int E, int NB) {
  __shared__ uint hist[NBMAX], lstart[NBMAX], cur[NBMAX], gbase[NBMAX];
  __shared__ uint ids[DC];
  __shared__ uint ts[256];
  int dir = blockIdx.x & 1;
  const int* key = dir ? senders : receivers;
  uint* g_cursor = dir ? gcur_s : gcur_r;
  uint* tmp = dir ? tmp_s : tmp_r;
  int t = threadIdx.x;
  int base = (blockIdx.x >> 1) * DC;
  int cact = min(DC, E - base);
  for (int i = t; i < NB; i += 256) hist[i] = 0;
  __syncthreads();
  for (int k = 0; k < DC / 256; ++k) {
    int j = k * 256 + t;
    if (j < cact) atomicAdd(&hist[key[base + j] >> BSHIFT], 1u);
  }
  __syncthreads();
  {
    uint loc[4]; uint tsum = 0;
    #pragma unroll
    for (int q = 0; q < 4; ++q) {
      int i = t * 4 + q;
      loc[q] = (i < NB) ? hist[i] : 0;
      tsum += loc[q];
    }
    ts[t] = tsum;
    __syncthreads();
    for (int off = 1; off < 256; off <<= 1) {
      uint a = (t >= off) ? ts[t - off] : 0;
      __syncthreads();
      ts[t] += a;
      __syncthreads();
    }
    uint run = ts[t] - tsum;
    #pragma unroll
    for (int q = 0; q < 4; ++q) {
      int i = t * 4 + q;
      if (i < NB) { lstart[i] = run; cur[i] = run; run += loc[q]; }
    }
  }
  __syncthreads();
  for (int i = t; i < NB; i += 256)
    if (hist[i]) gbase[i] = atomicAdd(&g_cursor[i], hist[i]);
  for (int k = 0; k < DC / 256; ++k) {
    int j = k * 256 + t;
    if (j < cact) {
      int e = base + j;
      uint b = (uint)(key[e] >> BSHIFT);
      uint slot = atomicAdd(&cur[b], 1u);
      ids[slot] = (b << 21) | (uint)e;
    }
  }
  __syncthreads();
  for (int j = t; j < cact; j += 256) {
    uint v = ids[j];
    uint b = v >> 21;
    tmp[gbase[b] + ((uint)j - lstart[b])] = v;
  }
}

// ---- per-bucket gather: 512 thr, 16 half-wave edge units, unroll 4.
__global__ __launch_bounds__(512) void gather_kernel(
    const ushort* __restrict__ e_h, const int* __restrict__ key,
    const uint* __restrict__ start, const uint* __restrict__ tmp,
    float* __restrict__ sum, uint* __restrict__ cnt, int N) {
  __shared__ float acc[BW * ASTRIDE];  // 33.3 KB
  __shared__ uint cntL[BW];
  const uint* eh32 = reinterpret_cast<const uint*>(e_h);
  int b = blockIdx.x;
  int t = threadIdx.x;
  for (int i = t; i < BW * ASTRIDE; i += 512) acc[i] = 0.f;
  if (t < BW) cntL[t] = 0;
  __syncthreads();
  int beg = (int)start[b], end = (int)start[b + 1];
  int u = t >> 5;    // edge unit 0..15
  int l = t & 31;    // column pair
  int i = beg + u;
  for (; i + 48 < end; i += 64) {
    uint v0 = tmp[i], v1 = tmp[i + 16], v2 = tmp[i + 32], v3 = tmp[i + 48];
    int e0 = (int)(v0 & EMASK), e1 = (int)(v1 & EMASK);
    int e2 = (int)(v2 & EMASK), e3 = (int)(v3 & EMASK);
    int r0 = key[e0] & (BW - 1), r1 = key[e1] & (BW - 1);
    int r2 = key[e2] & (BW - 1), r3 = key[e3] & (BW - 1);
    uint w0 = eh32[(size_t)e0 * 32 + l];
    uint w1 = eh32[(size_t)e1 * 32 + l];
    uint w2 = eh32[(size_t)e2 * 32 + l];
    uint w3 = eh32[(size_t)e3 * 32 + l];
    atomicAdd(&acc[r0 * ASTRIDE + 2 * l],     __uint_as_float(w0 << 16));
    atomicAdd(&acc[r0 * ASTRIDE + 2 * l + 1], __uint_as_float(w0 & 0xFFFF0000u));
    atomicAdd(&acc[r1 * ASTRIDE + 2 * l],     __uint_as_float(w1 << 16));
    atomicAdd(&acc[r1 * ASTRIDE + 2 * l + 1], __uint_as_float(w1 & 0xFFFF0000u));
    atomicAdd(&acc[r2 * ASTRIDE + 2 * l],     __uint_as_float(w2 << 16));
    atomicAdd(&acc[r2 * ASTRIDE + 2 * l + 1], __uint_as_float(w2 & 0xFFFF0000u));
    atomicAdd(&acc[r3 * ASTRIDE + 2 * l],     __uint_as_float(w3 << 16));
    atomicAdd(&acc[r3 * ASTRIDE + 2 * l + 1], __uint_as_float(w3 & 0xFFFF0000u));
    if (l == 0) {
      atomicAdd(&cntL[r0], 1u); atomicAdd(&cntL[r1], 1u);
      atomicAdd(&cntL[r2], 1u); atomicAdd(&cntL[r3], 1u);
    }
  }
  for (; i < end; i += 16) {
    uint v = tmp[i];
    int e = (int)(v & EMASK);
    int rl = key[e] & (BW - 1);
    uint w = eh32[(size_t)e * 32 + l];
    atomicAdd(&acc[rl * ASTRIDE + 2 * l],     __uint_as_float(w << 16));
    atomicAdd(&acc[rl * ASTRIDE + 2 * l + 1], __uint_as_float(w & 0xFFFF0000u));
    if (l == 0) atomicAdd(&cntL[rl], 1u);
  }
  __syncthreads();
  int nbase = b * BW;
  for (int i2 = t; i2 < BW * 64; i2 += 512) {
    int node = nbase + (i2 >> 6);
    if (node < N) sum[(size_t)node * 64 + (i2 & 63)] = acc[(i2 >> 6) * ASTRIDE + (i2 & 63)];
  }
  if (t < BW && nbase + t < N) cnt[nbase + t] = cntL[t];
}

// ---- node block
__global__ __launch_bounds__(256, 4) void node_kernel(
    const float* __restrict__ x, const float* __restrict__ sum_recv,
    const float* __restrict__ W_nb, const float* __restrict__ nb_init,
    float* __restrict__ n_h, int N) {
  int n = blockIdx.x * 256 + threadIdx.x;
  if (n >= N) return;
  float v[80];
  const float* ar = sum_recv + (size_t)n * 64;
  load16(ar, v); load16(ar + 16, v + 16); load16(ar + 32, v + 32);
  load16(ar + 48, v + 48);
  load16(x + (size_t)n * 16, v + 64);
  float* out = n_h + (size_t)n * 64;
  #pragma unroll
  for (int c = 0; c < 4; ++c) {
    float acc[16];
    #pragma unroll
    for (int j = 0; j < 16; ++j) acc[j] = nb_init[c * 16 + j];
    #pragma unroll
    for (int i = 0; i < 80; ++i) {
      const float* Wrow = W_nb + i * 64 + c * 16;
      #pragma unroll
      for (int j = 0; j < 16; ++j) acc[j] = fmaf(v[i], Wrow[j], acc[j]);
    }
    #pragma unroll
    for (int j = 0; j < 16; j += 4) {
      float4 tq = {fmaxf(acc[j], 0.f), fmaxf(acc[j + 1], 0.f),
                   fmaxf(acc[j + 2], 0.f), fmaxf(acc[j + 3], 0.f)};
      *reinterpret_cast<float4*>(out + c * 16 + j) = tq;
    }
  }
}

// ---- column sums of sum_recv (= sum of all e_h) and n_h
__global__ __launch_bounds__(256) void reduce_kernel(
    const float* __restrict__ sum_recv, const float* __restrict__ n_h,
    float* __restrict__ e_sum, float* __restrict__ n_sum, int N) {
  __shared__ float ls[128];
  if (threadIdx.x < 128) ls[threadIdx.x] = 0.f;
  __syncthreads();
  int g = threadIdx.x & 15;
  int tid = blockIdx.x * blockDim.x + threadIdx.x;
  int row0 = tid >> 4;
  int rstride = (gridDim.x * blockDim.x) >> 4;
  float pe[4] = {0, 0, 0, 0}, pn[4] = {0, 0, 0, 0};
  for (int r = row0; r < N; r += rstride) {
    float4 a = LDF4(sum_recv + (size_t)r * 64 + g * 4);
    float4 b = LDF4(n_h + (size_t)r * 64 + g * 4);
    pe[0] += a.x; pe[1] += a.y; pe[2] += a.z; pe[3] += a.w;
    pn[0] += b.x; pn[1] += b.y; pn[2] += b.z; pn[3] += b.w;
  }
  #pragma unroll
  for (int i = 0; i < 4; ++i) {
    atomicAdd(&ls[g * 4 + i], pe[i]);
    atomicAdd(&ls[64 + g * 4 + i], pn[i]);
  }
  __syncthreads();
  if (threadIdx.x < 64) {
    atomicAdd(&e_sum[threadIdx.x], ls[threadIdx.x]);
    atomicAdd(&n_sum[threadIdx.x], ls[64 + threadIdx.x]);
  }
}

// ---- global block + fold u2 into d1_init
__global__ void global_kernel(const float* __restrict__ u,
                              const float* __restrict__ e_sum,
                              const float* __restrict__ n_sum,
                              const float* __restrict__ W_gb,
                              const float* __restrict__ b_gb,
                              const float* __restrict__ W_d1,
                              const float* __restrict__ b_d1,
                              float* __restrict__ d1_init, float Ef, float Nf) {
  __shared__ float gin[192];
  __shared__ float u2s[64];
  int j = threadIdx.x;  // 64 threads
  gin[j] = e_sum[j] / Ef;
  gin[64 + j] = n_sum[j] / Nf;
  gin[128 + j] = u[j];
  __syncthreads();
  float a = b_gb[j];
  for (int k = 0; k < 192; ++k) a = fmaf(gin[k], W_gb[k * 64 + j], a);
  u2s[j] = fmaxf(a, 0.f);
  __syncthreads();
  float d = b_d1[j];
  for (int k = 0; k < 64; ++k) d = fmaf(u2s[k], W_d1[(192 + k) * 64 + j], d);
  d1_init[j] = d;
}

// ---- decoder
__global__ __launch_bounds__(256, 2) void decoder_kernel(
    const float* __restrict__ sum_recv, const float* __restrict__ sum_sent,
    const uint* __restrict__ cnt_r, const uint* __restrict__ cnt_s,
    const float* __restrict__ n_h, const float* __restrict__ W_d1,
    const float* __restrict__ d1_init, const float* __restrict__ W_d2,
    const float* __restrict__ b_d2, float* __restrict__ out, int N) {
  int n = blockIdx.x * 256 + threadIdx.x;
  if (n >= N) return;
  float acc[64];
  #pragma unroll
  for (int j = 0; j < 64; ++j) acc[j] = d1_init[j];
  float v[16];
  float invr = 1.0f / fmaxf((float)cnt_r[n], 1.0f);
  const float* pr = sum_recv + (size_t)n * 64;
  #pragma unroll
  for (int c = 0; c < 4; ++c) {
    load16(pr + c * 16, v);
    #pragma unroll
    for (int i = 0; i < 16; ++i) v[i] *= invr;
    #pragma unroll
    for (int i = 0; i < 16; ++i) {
      const float* Wrow = W_d1 + (c * 16 + i) * 64;
      #pragma unroll
      for (int j = 0; j < 64; ++j) acc[j] = fmaf(v[i], Wrow[j], acc[j]);
    }
  }
  float invs = 1.0f / fmaxf((float)cnt_s[n], 1.0f);
  const float* ps = sum_sent + (size_t)n * 64;
  #pragma unroll
  for (int c = 0; c < 4; ++c) {
    load16(ps + c * 16, v);
    #pragma unroll
    for (int i = 0; i < 16; ++i) v[i] *= invs;
    #pragma unroll
    for (int i = 0; i < 16; ++i) {
      const float* Wrow = W_d1 + (64 + c * 16 + i) * 64;
      #pragma unroll
      for (int j = 0; j < 64; ++j) acc[j] = fmaf(v[i], Wrow[j], acc[j]);
    }
  }
  const float* pn = n_h + (size_t)n * 64;
  #pragma unroll
  for (int c = 0; c < 4; ++c) {
    load16(pn + c * 16, v);
    #pragma unroll
    for (int i = 0; i < 16; ++i) {
      const float* Wrow = W_d1 + (128 + c * 16 + i) * 64;
      #pragma unroll
      for (int j = 0; j < 64; ++j) acc[j] = fmaf(v[i], Wrow[j], acc[j]);
    }
  }
  #pragma unroll
  for (int j = 0; j < 64; ++j) acc[j] = fmaxf(acc[j], 0.f);
  float* po = out + (size_t)n * 16;
  #pragma unroll
  for (int o = 0; o < 16; o += 4) {
    float4 tq;
    float* tp = &tq.x;
    #pragma unroll
    for (int q = 0; q < 4; ++q) {
      float a = b_d2[o + q];
      #pragma unroll
      for (int j = 0; j < 64; ++j) a = fmaf(acc[j], W_d2[j * 16 + o + q], a);
      tp[q] = a;
    }
    *reinterpret_cast<float4*>(po + o) = tq;
  }
}

extern "C" void kernel_launch(void* const* d_in, const int* in_sizes, int n_in,
                              void* d_out, int out_size, void* d_ws,
                              size_t ws_size, hipStream_t stream) {
  const float* x         = (const float*)d_in[0];
  const float* edge_attr = (const float*)d_in[1];
  const float* u         = (const float*)d_in[2];
  const int*   senders   = (const int*)d_in[3];
  const int*   receivers = (const int*)d_in[4];
  const float* W_eb = (const float*)d_in[7];
  const float* b_eb = (const float*)d_in[8];
  const float* W_nb = (const float*)d_in[9];
  const float* b_nb = (const float*)d_in[10];
  const float* W_gb = (const float*)d_in[11];
  const float* b_gb = (const float*)d_in[12];
  const float* W_d1 = (const float*)d_in[13];
  const float* b_d1 = (const float*)d_in[14];
  const float* W_d2 = (const float*)d_in[15];
  const float* b_d2 = (const float*)d_in[16];

  int N = in_sizes[0] / 16;
  int E = in_sizes[1] / 16;
  int NB = (N + BW - 1) >> BSHIFT;  // 782 for N=100000
  int NDB = (E + DC - 1) / DC;      // distribute chunks per direction

  char* w = (char*)d_ws;
  ushort* e_h = (ushort*)w;          w += (size_t)E * 64 * 2;
  float* sum_recv = (float*)w;       w += (size_t)N * 64 * 4;
  float* sum_sent = (float*)w;       w += (size_t)N * 64 * 4;
  float* n_h = (float*)w;            w += (size_t)N * 64 * 4;
  uint* tmp_r = (uint*)w;            w += (size_t)E * 4;
  uint* tmp_s = (uint*)w;            w += (size_t)E * 4;
  uint* start_r = (uint*)w;          w += (size_t)(NB + 1) * 4;
  uint* start_s = (uint*)w;          w += (size_t)(NB + 1) * 4;
  uint* cur_r = (uint*)w;            w += (size_t)NB * 4;
  uint* cur_s = (uint*)w;            w += (size_t)NB * 4;
  uint* cnt_r = (uint*)w;            w += (size_t)N * 4;
  uint* cnt_s = (uint*)w;            w += (size_t)N * 4;
  // zeroed region
  uint* bcnt_r = (uint*)w;           w += (size_t)NBMAX * 4;
  uint* bcnt_s = (uint*)w;           w += (size_t)NBMAX * 4;
  float* e_sum = (float*)w;          w += 64 * 4;
  float* n_sum = (float*)w;          w += 64 * 4;
  // small non-zeroed
  float* eb_init = (float*)w;        w += 64 * 4;
  float* nb_init = (float*)w;        w += 64 * 4;
  float* d1_init = (float*)w;        w += 64 * 4;

  size_t zero_bytes = (size_t)(2 * NBMAX + 128) * 4;
  hipMemsetAsync(bcnt_r, 0, zero_bytes, stream);

  hipLaunchKernelGGL(precompute_kernel, dim3(1), dim3(64), 0, stream, u, W_eb,
                     b_eb, W_nb, b_nb, eb_init, nb_init);
  hipLaunchKernelGGL(edge_kernel, dim3((E + 255) / 256), dim3(256), 0, stream,
                     edge_attr, x, senders, receivers, W_eb, eb_init, e_h, E);
  hipLaunchKernelGGL(bcount_kernel, dim3(64), dim3(256), 0, stream, receivers,
                     senders, bcnt_r, bcnt_s, E, NB);
  hipLaunchKernelGGL(bscan_kernel, dim3(1), dim3(256), 0, stream, bcnt_r,
                     bcnt_s, start_r, start_s, cur_r, cur_s, E, NB);
  hipLaunchKernelGGL(distribute_kernel, dim3(2 * NDB), dim3(256), 0, stream,
                     receivers, senders, cur_r, cur_s, tmp_r, tmp_s, E, NB);
  hipLaunchKernelGGL(gather_kernel, dim3(NB), dim3(512), 0, stream, e_h,
                     receivers, start_r, tmp_r, sum_recv, cnt_r, N);
  hipLaunchKernelGGL(gather_kernel, dim3(NB), dim3(512), 0, stream, e_h,
                     senders, start_s, tmp_s, sum_sent, cnt_s, N);
  hipLaunchKernelGGL(node_kernel, dim3((N + 255) / 256), dim3(256), 0, stream,
                     x, sum_recv, W_nb, nb_init, n_h, N);
  hipLaunchKernelGGL(reduce_kernel, dim3(256), dim3(256), 0, stream, sum_recv,
                     n_h, e_sum, n_sum, N);
  hipLaunchKernelGGL(global_kernel, dim3(1), dim3(64), 0, stream, u, e_sum,
                     n_sum, W_gb, b_gb, W_d1, b_d1, d1_init, (float)E,
                     (float)N);
  hipLaunchKernelGGL(decoder_kernel, dim3((N + 255) / 256), dim3(256), 0,
                     stream, sum_recv, sum_sent, cnt_r, cnt_s, n_h, W_d1,
                     d1_init, W_d2, b_d2, (float*)d_out, N);
}